// Round 17
// baseline (68.542 us; speedup 1.0000x reference)
//
#include <hip/hip_runtime.h>

// SparseMatmul3D: out[b,n,m] = sum_k x[b,n,k] * y[b,m,k]
// B=4, N=M=4096, D=64, fp32 in/out.
// MODEL (fits R1-R16): every dwordx4 vmem instr costs ~40ns of CU port time
//   at chip saturation, loads==stores, L2-hit or not. Time ~ total vmem bytes
//   / 6.7 TB/s. R16 (256x256 LDS GEMM): 396 MB -> 57.5us observed.
// R17: 512x512 tiles -> loads 128->67 MB, total 335 MB -> ~50us predicted.
//   256 blocks (1/CU), 128 KB LDS bf16 panels, ONE barrier before any store,
//   8 register-tiled passes, stores never drained (ds_read is lgkm-domain).

#define BATCH 4
#define NN 4096
#define MM 4096
#define DD 64

typedef __attribute__((ext_vector_type(8))) short bf16x8;
typedef __attribute__((ext_vector_type(4))) float f32x4;

__device__ __forceinline__ unsigned short f2bf(float f) {
    unsigned u = __builtin_bit_cast(unsigned, f);
    u += 0x7FFFu + ((u >> 16) & 1u);   // round-to-nearest-even
    return (unsigned short)(u >> 16);
}

__device__ __forceinline__ bf16x8 cvt8(f32x4 v0, f32x4 v1) {
    bf16x8 r;
    r[0] = (short)f2bf(v0[0]); r[1] = (short)f2bf(v0[1]);
    r[2] = (short)f2bf(v0[2]); r[3] = (short)f2bf(v0[3]);
    r[4] = (short)f2bf(v1[0]); r[5] = (short)f2bf(v1[1]);
    r[6] = (short)f2bf(v1[2]); r[7] = (short)f2bf(v1[3]);
    return r;
}

// Stage one 512x64-f32 contiguous panel into XOR-swizzled bf16 LDS (R16 scheme).
// Thread t, iter u: f32 [u*4096 + t*8, +8) -> row r=f/64, unit (t&7)^(r&7).
__device__ __forceinline__ void stage_panel(const float* __restrict__ src,
                                            short* __restrict__ dst, int t) {
#pragma unroll
    for (int u = 0; u < 8; ++u) {
        const int f = u * 4096 + t * 8;
        f32x4 v0 = *reinterpret_cast<const f32x4*>(src + f);
        f32x4 v1 = *reinterpret_cast<const f32x4*>(src + f + 4);
        const int r  = (u << 6) + (t >> 3);
        const int un = (t & 7) ^ (r & 7);
        *reinterpret_cast<bf16x8*>(&dst[r * 64 + un * 8]) = cvt8(v0, v1);
    }
}

__global__ __launch_bounds__(512, 1) void
SparseMatmul3D_36155034698289_kernel(const float* __restrict__ x,
                                     const float* __restrict__ y,
                                     float* __restrict__ out) {
    const int bid = blockIdx.x;          // [0,256)
    const int mc  = bid & 7;             // m-tile (fastest)
    const int nt  = (bid >> 3) & 7;      // n-tile
    const int b   = bid >> 6;            // batch
    const int n0  = nt * 512;
    const int m0  = mc * 512;

    const int tid   = threadIdx.x;
    const int w     = tid >> 6;          // 8 waves
    const int lane  = tid & 63;
    const int row16 = lane & 15;
    const int kgrp  = lane >> 4;
    const int wr    = w >> 1;            // n sub-band [0,4)
    const int wc    = w & 1;             // m sub-band [0,2)

    __shared__ short xs[512 * 64];       // 64 KB bf16 x-panel (n rows)
    __shared__ short ys[512 * 64];       // 64 KB bf16 y-panel (m rows)

    stage_panel(x + (size_t)b * NN * DD + (size_t)n0 * DD, xs, tid);
    stage_panel(y + (size_t)b * MM * DD + (size_t)m0 * DD, ys, tid);
    __syncthreads();   // only barrier; no stores in flight yet

    float* __restrict__ ob = out + (size_t)b * NN * MM;

    // 8 passes: pn in {0,1} (n half), pm in {0..3} (m quarter).
    // Per pass each wave computes a 64x64 subtile (acc[4][4], R8-proven math).
#pragma unroll
    for (int p = 0; p < 8; ++p) {
        const int pn   = p & 1;
        const int pm   = p >> 1;
        const int nloc = pn * 256 + wr * 64;
        const int mloc = pm * 128 + wc * 64;

        f32x4 acc[4][4];
#pragma unroll
        for (int i = 0; i < 4; ++i)
#pragma unroll
            for (int j = 0; j < 4; ++j)
                acc[i][j] = (f32x4){0.f, 0.f, 0.f, 0.f};

#pragma unroll
        for (int i = 0; i < 4; ++i) {
            const int ra = mloc + i * 16 + row16;
            const bf16x8 a0 = *reinterpret_cast<const bf16x8*>(
                &ys[ra * 64 + ((kgrp       ^ (ra & 7)) * 8)]);
            const bf16x8 a1 = *reinterpret_cast<const bf16x8*>(
                &ys[ra * 64 + (((4 | kgrp) ^ (ra & 7)) * 8)]);
#pragma unroll
            for (int j = 0; j < 4; ++j) {
                const int rb = nloc + j * 16 + row16;
                const bf16x8 b0 = *reinterpret_cast<const bf16x8*>(
                    &xs[rb * 64 + ((kgrp       ^ (rb & 7)) * 8)]);
                const bf16x8 b1 = *reinterpret_cast<const bf16x8*>(
                    &xs[rb * 64 + (((4 | kgrp) ^ (rb & 7)) * 8)]);
                acc[i][j] = __builtin_amdgcn_mfma_f32_16x16x32_bf16(
                    a0, b0, acc[i][j], 0, 0, 0);
                acc[i][j] = __builtin_amdgcn_mfma_f32_16x16x32_bf16(
                    a1, b1, acc[i][j], 0, 0, 0);
            }
        }

        // D layout: col=lane&15=n, row=kgrp*4+reg=m (4 consecutive m).
#pragma unroll
        for (int j = 0; j < 4; ++j) {
            float* orow = ob + (size_t)(n0 + nloc + j * 16 + row16) * MM;
#pragma unroll
            for (int i = 0; i < 4; ++i)
                *reinterpret_cast<f32x4*>(
                    orow + m0 + mloc + i * 16 + kgrp * 4) = acc[i][j];
        }
    }
}

extern "C" void kernel_launch(void* const* d_in, const int* in_sizes, int n_in,
                              void* d_out, int out_size, void* d_ws, size_t ws_size,
                              hipStream_t stream) {
    const float* x = (const float*)d_in[0];
    const float* y = (const float*)d_in[1];
    float* out = (float*)d_out;

    dim3 grid(256);
    dim3 block(512);
    SparseMatmul3D_36155034698289_kernel<<<grid, block, 0, stream>>>(x, y, out);
}

// Round 18
// 66.251 us; speedup vs baseline: 1.0346x; 1.0346x over previous
//
#include <hip/hip_runtime.h>

// SparseMatmul3D: out[b,n,m] = sum_k x[b,n,k] * y[b,m,k]
// B=4, N=M=4096, D=64, fp32 in/out.
// MODEL (fits R1-R17): time ~ total issued vmem bytes / 6.7 TB/s, loads cost
//   the same CU-port time as stores (L2-hit or not) — PROVIDED ~16 waves/CU
//   keep the port fed. R16 (396 MB, 16 w/CU) = 57.5us. R17 (335 MB but only
//   8 w/CU) = 68.5us: issue concurrency starved the port.
// R18: 512x512 tile (335 MB total) with 1024-thread blocks = 16 waves/CU.
//   Stage 128 KB swizzled bf16 panels -> one barrier -> 4 passes/wave of
//   {ds_read frags, 32 MFMA, 16 stores}; stores never drained.

#define BATCH 4
#define NN 4096
#define MM 4096
#define DD 64

typedef __attribute__((ext_vector_type(8))) short bf16x8;
typedef __attribute__((ext_vector_type(4))) float f32x4;

__device__ __forceinline__ unsigned short f2bf(float f) {
    unsigned u = __builtin_bit_cast(unsigned, f);
    u += 0x7FFFu + ((u >> 16) & 1u);   // round-to-nearest-even
    return (unsigned short)(u >> 16);
}

__device__ __forceinline__ bf16x8 cvt8(f32x4 v0, f32x4 v1) {
    bf16x8 r;
    r[0] = (short)f2bf(v0[0]); r[1] = (short)f2bf(v0[1]);
    r[2] = (short)f2bf(v0[2]); r[3] = (short)f2bf(v0[3]);
    r[4] = (short)f2bf(v1[0]); r[5] = (short)f2bf(v1[1]);
    r[6] = (short)f2bf(v1[2]); r[7] = (short)f2bf(v1[3]);
    return r;
}

// Stage one 512x64-f32 contiguous panel into XOR-swizzled bf16 LDS.
// 1024 threads, 4 iters: thread t, iter u covers f32 [u*8192 + t*8, +8).
// row r = f/64, unit (t&7)^(r&7) — bijective, matches ds_read swizzle below.
__device__ __forceinline__ void stage_panel(const float* __restrict__ src,
                                            short* __restrict__ dst, int t) {
#pragma unroll
    for (int u = 0; u < 4; ++u) {
        const int f = u * 8192 + t * 8;
        f32x4 v0 = *reinterpret_cast<const f32x4*>(src + f);
        f32x4 v1 = *reinterpret_cast<const f32x4*>(src + f + 4);
        const int r  = (u << 7) + (t >> 3);
        const int un = (t & 7) ^ (r & 7);
        *reinterpret_cast<bf16x8*>(&dst[r * 64 + un * 8]) = cvt8(v0, v1);
    }
}

__global__ __launch_bounds__(1024, 4) void
SparseMatmul3D_36155034698289_kernel(const float* __restrict__ x,
                                     const float* __restrict__ y,
                                     float* __restrict__ out) {
    const int bid = blockIdx.x;          // [0,256)
    const int mc  = bid & 7;             // m-tile (fastest)
    const int nt  = (bid >> 3) & 7;      // n-tile
    const int b   = bid >> 6;            // batch
    const int n0  = nt * 512;
    const int m0  = mc * 512;

    const int tid   = threadIdx.x;
    const int w     = tid >> 6;          // 16 waves
    const int lane  = tid & 63;
    const int row16 = lane & 15;
    const int kgrp  = lane >> 4;

    __shared__ short xs[512 * 64];       // 64 KB bf16 x-panel (n rows)
    __shared__ short ys[512 * 64];       // 64 KB bf16 y-panel (m rows)

    stage_panel(x + (size_t)b * NN * DD + (size_t)n0 * DD, xs, tid);
    stage_panel(y + (size_t)b * MM * DD + (size_t)m0 * DD, ys, tid);
    __syncthreads();   // only barrier; no stores in flight yet

    float* __restrict__ ob = out + (size_t)b * NN * MM;

    // 4 passes; wave w owns 64x64 subtile at
    //   nloc = (w>>2)*64 + (p&1)*256,  mloc = (w&3)*64 + (p>>1)*256
#pragma unroll
    for (int p = 0; p < 4; ++p) {
        const int nloc = (w >> 2) * 64 + (p & 1) * 256;
        const int mloc = (w & 3) * 64 + (p >> 1) * 256;

        f32x4 acc[4][4];
#pragma unroll
        for (int i = 0; i < 4; ++i)
#pragma unroll
            for (int j = 0; j < 4; ++j)
                acc[i][j] = (f32x4){0.f, 0.f, 0.f, 0.f};

#pragma unroll
        for (int i = 0; i < 4; ++i) {
            const int ra = mloc + i * 16 + row16;
            const bf16x8 a0 = *reinterpret_cast<const bf16x8*>(
                &ys[ra * 64 + ((kgrp       ^ (ra & 7)) * 8)]);
            const bf16x8 a1 = *reinterpret_cast<const bf16x8*>(
                &ys[ra * 64 + (((4 | kgrp) ^ (ra & 7)) * 8)]);
#pragma unroll
            for (int j = 0; j < 4; ++j) {
                const int rb = nloc + j * 16 + row16;
                const bf16x8 b0 = *reinterpret_cast<const bf16x8*>(
                    &xs[rb * 64 + ((kgrp       ^ (rb & 7)) * 8)]);
                const bf16x8 b1 = *reinterpret_cast<const bf16x8*>(
                    &xs[rb * 64 + (((4 | kgrp) ^ (rb & 7)) * 8)]);
                acc[i][j] = __builtin_amdgcn_mfma_f32_16x16x32_bf16(
                    a0, b0, acc[i][j], 0, 0, 0);
                acc[i][j] = __builtin_amdgcn_mfma_f32_16x16x32_bf16(
                    a1, b1, acc[i][j], 0, 0, 0);
            }
        }

        // D layout: col=lane&15=n, row=kgrp*4+reg=m (4 consecutive m).
#pragma unroll
        for (int j = 0; j < 4; ++j) {
            float* orow = ob + (size_t)(n0 + nloc + j * 16 + row16) * MM;
#pragma unroll
            for (int i = 0; i < 4; ++i)
                *reinterpret_cast<f32x4*>(
                    orow + m0 + mloc + i * 16 + kgrp * 4) = acc[i][j];
        }
    }
}

extern "C" void kernel_launch(void* const* d_in, const int* in_sizes, int n_in,
                              void* d_out, int out_size, void* d_ws, size_t ws_size,
                              hipStream_t stream) {
    const float* x = (const float*)d_in[0];
    const float* y = (const float*)d_in[1];
    float* out = (float*)d_out;

    dim3 grid(256);
    dim3 block(1024);
    SparseMatmul3D_36155034698289_kernel<<<grid, block, 0, stream>>>(x, y, out);
}

// Round 19
// 58.864 us; speedup vs baseline: 1.1644x; 1.1255x over previous
//
#include <hip/hip_runtime.h>

// SparseMatmul3D: out[b,n,m] = sum_k x[b,n,k] * y[b,m,k]
// B=4, N=M=4096, D=64, fp32 in/out.
// MODEL (fits R1-R18): time ~ total issued vmem bytes / ~6.9 TB/s, PROVIDED
//   stores are always available to issue (R16's 2-blocks/CU x 4 generations
//   pipelining). R16 (396 MB) = 57.5us. R17/R18 single-generation = 66-68us
//   (stage phase serialized against store phase).
// R19: R16 compute/store body VERBATIM + bf16 pre-swizzled scratch prologue:
//   x,y (8 MB f32) -> 4 MB bf16 in d_ws, already in LDS swizzle order, so the
//   main stage is a linear 16B copy. Loads 128->67 MB; total 347 MB -> ~52us.
//   Fallback to exact R16 if ws_size < 4 MB.

#define BATCH 4
#define NN 4096
#define MM 4096
#define DD 64

typedef __attribute__((ext_vector_type(8))) short bf16x8;
typedef __attribute__((ext_vector_type(4))) float f32x4;

__device__ __forceinline__ unsigned short f2bf(float f) {
    unsigned u = __builtin_bit_cast(unsigned, f);
    u += 0x7FFFu + ((u >> 16) & 1u);   // round-to-nearest-even
    return (unsigned short)(u >> 16);
}

__device__ __forceinline__ bf16x8 cvt8(f32x4 v0, f32x4 v1) {
    bf16x8 r;
    r[0] = (short)f2bf(v0[0]); r[1] = (short)f2bf(v0[1]);
    r[2] = (short)f2bf(v0[2]); r[3] = (short)f2bf(v0[3]);
    r[4] = (short)f2bf(v1[0]); r[5] = (short)f2bf(v1[1]);
    r[6] = (short)f2bf(v1[2]); r[7] = (short)f2bf(v1[3]);
    return r;
}

// ---- prologue: f32 -> bf16, pre-swizzled unit order (unit u of row R goes to
// unit u^(R&7)). 131072 threads, each converts one 8-elem unit of x and of y.
__global__ __launch_bounds__(256) void
preswz_kernel(const float* __restrict__ x, const float* __restrict__ y,
              short* __restrict__ xscr, short* __restrict__ yscr) {
    const int t = blockIdx.x * 256 + threadIdx.x;   // [0, 131072)
    const int R = t >> 3;
    const int u = t & 7;
    const int dst = R * 64 + ((u ^ (R & 7)) << 3);
    {
        const float* p = x + (size_t)t * 8;
        f32x4 v0 = *reinterpret_cast<const f32x4*>(p);
        f32x4 v1 = *reinterpret_cast<const f32x4*>(p + 4);
        *reinterpret_cast<bf16x8*>(&xscr[dst]) = cvt8(v0, v1);
    }
    {
        const float* p = y + (size_t)t * 8;
        f32x4 v0 = *reinterpret_cast<const f32x4*>(p);
        f32x4 v1 = *reinterpret_cast<const f32x4*>(p + 4);
        *reinterpret_cast<bf16x8*>(&yscr[dst]) = cvt8(v0, v1);
    }
}

// ---- shared compute/store body (R16 verbatim) ----
__device__ __forceinline__ void
compute_and_store(const short* __restrict__ xs, const short* __restrict__ ys,
                  float* __restrict__ ob, int n0, int m0, int w, int lane) {
    const int row16 = lane & 15;
    const int kgrp  = lane >> 4;
    const int wr    = w >> 1;            // n quarter [0,4)
    const int wcp   = (w & 1) * 2;       // m subtile pair base
    const int nloc  = wr * 64;

#pragma unroll
    for (int tt = 0; tt < 2; ++tt) {
        const int mloc = (wcp + tt) * 64;

        f32x4 acc[4][4];
#pragma unroll
        for (int i = 0; i < 4; ++i)
#pragma unroll
            for (int j = 0; j < 4; ++j)
                acc[i][j] = (f32x4){0.f, 0.f, 0.f, 0.f};

#pragma unroll
        for (int i = 0; i < 4; ++i) {
            const int ra = mloc + i * 16 + row16;
            const bf16x8 a0 = *reinterpret_cast<const bf16x8*>(
                &ys[ra * 64 + ((kgrp       ^ (ra & 7)) * 8)]);
            const bf16x8 a1 = *reinterpret_cast<const bf16x8*>(
                &ys[ra * 64 + (((4 | kgrp) ^ (ra & 7)) * 8)]);
#pragma unroll
            for (int j = 0; j < 4; ++j) {
                const int rb = nloc + j * 16 + row16;
                const bf16x8 b0 = *reinterpret_cast<const bf16x8*>(
                    &xs[rb * 64 + ((kgrp       ^ (rb & 7)) * 8)]);
                const bf16x8 b1 = *reinterpret_cast<const bf16x8*>(
                    &xs[rb * 64 + (((4 | kgrp) ^ (rb & 7)) * 8)]);
                acc[i][j] = __builtin_amdgcn_mfma_f32_16x16x32_bf16(
                    a0, b0, acc[i][j], 0, 0, 0);
                acc[i][j] = __builtin_amdgcn_mfma_f32_16x16x32_bf16(
                    a1, b1, acc[i][j], 0, 0, 0);
            }
        }

        // D layout: col=lane&15=n, row=kgrp*4+reg=m (4 consecutive m).
#pragma unroll
        for (int j = 0; j < 4; ++j) {
            float* orow = ob + (size_t)(nloc + j * 16 + row16) * MM;
#pragma unroll
            for (int i = 0; i < 4; ++i)
                *reinterpret_cast<f32x4*>(
                    orow + m0 + mloc + i * 16 + kgrp * 4) = acc[i][j];
        }
    }
}

// ---- main kernel, scratch path: linear 16B copy of pre-swizzled bf16 panels
__global__ __launch_bounds__(512, 4) void
SparseMatmul3D_36155034698289_kernel(const short* __restrict__ xscr,
                                     const short* __restrict__ yscr,
                                     float* __restrict__ out) {
    const int bid = blockIdx.x;          // [0,1024)
    const int mc  = bid & 15;
    const int nt  = (bid >> 4) & 15;
    const int b   = bid >> 8;
    const int n0  = nt * 256;
    const int m0  = mc * 256;

    const int tid  = threadIdx.x;
    const int w    = tid >> 6;
    const int lane = tid & 63;

    __shared__ short xs[256 * 64];       // 32 KB bf16 x-panel
    __shared__ short ys[256 * 64];       // 32 KB bf16 y-panel

    {
        const bf16x8* xsrc = reinterpret_cast<const bf16x8*>(
            xscr + (size_t)(b * NN + n0) * DD);
        const bf16x8* ysrc = reinterpret_cast<const bf16x8*>(
            yscr + (size_t)(b * MM + m0) * DD);
        bf16x8* xdst = reinterpret_cast<bf16x8*>(xs);
        bf16x8* ydst = reinterpret_cast<bf16x8*>(ys);
#pragma unroll
        for (int u = 0; u < 4; ++u) {
            xdst[u * 512 + tid] = xsrc[u * 512 + tid];
            ydst[u * 512 + tid] = ysrc[u * 512 + tid];
        }
    }
    __syncthreads();   // only barrier; no stores in flight yet

    compute_and_store(xs, ys, out + (size_t)b * NN * MM + (size_t)n0 * MM,
                      n0, m0, w, lane);
}

// ---- fallback: exact R16 (f32 inputs staged with in-kernel cvt+swizzle) ----
__device__ __forceinline__ void stage_panel(const float* __restrict__ src,
                                            short* __restrict__ dst, int t) {
#pragma unroll
    for (int u = 0; u < 4; ++u) {
        const int f = u * 4096 + t * 8;
        f32x4 v0 = *reinterpret_cast<const f32x4*>(src + f);
        f32x4 v1 = *reinterpret_cast<const f32x4*>(src + f + 4);
        const int r  = (u << 6) + (t >> 3);
        const int un = (t & 7) ^ (r & 7);
        *reinterpret_cast<bf16x8*>(&dst[r * 64 + un * 8]) = cvt8(v0, v1);
    }
}

__global__ __launch_bounds__(512, 4) void
sparse_mm_direct_kernel(const float* __restrict__ x, const float* __restrict__ y,
                        float* __restrict__ out) {
    const int bid = blockIdx.x;
    const int mc  = bid & 15;
    const int nt  = (bid >> 4) & 15;
    const int b   = bid >> 8;
    const int n0  = nt * 256;
    const int m0  = mc * 256;

    const int tid  = threadIdx.x;
    const int w    = tid >> 6;
    const int lane = tid & 63;

    __shared__ short xs[256 * 64];
    __shared__ short ys[256 * 64];

    stage_panel(x + (size_t)b * NN * DD + (size_t)n0 * DD, xs, tid);
    stage_panel(y + (size_t)b * MM * DD + (size_t)m0 * DD, ys, tid);
    __syncthreads();

    compute_and_store(xs, ys, out + (size_t)b * NN * MM + (size_t)n0 * MM,
                      n0, m0, w, lane);
}

extern "C" void kernel_launch(void* const* d_in, const int* in_sizes, int n_in,
                              void* d_out, int out_size, void* d_ws, size_t ws_size,
                              hipStream_t stream) {
    const float* x = (const float*)d_in[0];
    const float* y = (const float*)d_in[1];
    float* out = (float*)d_out;

    if (ws_size >= (size_t)4 * 1024 * 1024) {
        short* xscr = (short*)d_ws;                      // 2 MB
        short* yscr = (short*)d_ws + (size_t)BATCH * NN * DD;  // 2 MB
        preswz_kernel<<<dim3(512), dim3(256), 0, stream>>>(x, y, xscr, yscr);
        SparseMatmul3D_36155034698289_kernel<<<dim3(1024), dim3(512), 0, stream>>>(
            xscr, yscr, out);
    } else {
        sparse_mm_direct_kernel<<<dim3(1024), dim3(512), 0, stream>>>(x, y, out);
    }
}